// Round 9
// baseline (25.916 us; speedup 1.0000x reference)
//
#include <hip/hip_runtime.h>
#include <hip/hip_bf16.h>
#include <math.h>

typedef __attribute__((ext_vector_type(8)))  short bf16x8;
typedef __attribute__((ext_vector_type(16))) float f32x16;
typedef unsigned int u32;

#define KAPPA (1.0f/61.0f)
#define NBLK 256           // 32768 rows / 128 rows-per-block
// swap bits 2<->3 of a 5-bit row index (pre-D row -> B-frag k-order fixup)
#define SWAP23(r) (((r) & 19) | (((r) & 4) << 1) | (((r) & 8) >> 1))

__device__ __forceinline__ unsigned short f2bf(float f) {
    u32 x = __float_as_uint(f);
    x += 0x7fffu + ((x >> 16) & 1u);               // RNE
    return (unsigned short)(x >> 16);
}
__device__ __forceinline__ float fast_rcp(float v) {
#if __has_builtin(__builtin_amdgcn_rcpf)
    return __builtin_amdgcn_rcpf(v);
#else
    return 1.0f / v;
#endif
}
__device__ __forceinline__ u32 pack_bf16(float lo, float hi) {
    __hip_bfloat162 p = __float22bfloat162_rn(make_float2(lo, hi));  // v_cvt_pk path
    return *reinterpret_cast<u32*>(&p);
}

// ---------------------------------------------------------------------------
// Kernel 1: precompute MFMA operand fragments (all sample-independent).
//  V  frags [16384]: f=(kkg*8+ptile)*64+lane -> A-frag of V^T:
//       row p = ptile*32+(lane&31), k h = kkg*16+(lane>>5)*8+i
//       V[h][p] = W1[l][h]*W2[h][c], p=l*35+c (pad 245->256)
//  Wt frags [1024]:  f=htile*64+lane -> A-frag of [W1^T | b1] with PERMUTED
//       rows: row r -> h = htile*32 + SWAP23(r), so the pre-MFMA's packed
//       D output is directly the main-GEMM B-fragment (no shuffle/scatter).
//       lo half k=0..6 -> W1[k][h], k=7 -> b1[h]; hi half 0.
// ---------------------------------------------------------------------------
__global__ void build_v(const float* __restrict__ W1, const float* __restrict__ W2,
                        const float* __restrict__ b1,
                        bf16x8* __restrict__ V, bf16x8* __restrict__ Wt) {
    int t = blockIdx.x * blockDim.x + threadIdx.x;
    if (t < 16384) {
        int lane = t & 63, ptile = (t >> 6) & 7, kkg = t >> 9;
        int p  = ptile * 32 + (lane & 31);
        int hb = kkg * 16 + (lane >> 5) * 8;
        bool valid = (p < 245);
        int l7 = valid ? p / 35 : 0;
        int c  = valid ? p - l7 * 35 : 0;
        bf16x8 v;
#pragma unroll
        for (int i = 0; i < 8; ++i) {
            int h = hb + i;
            v[i] = valid ? (short)f2bf(W1[l7 * 512 + h] * W2[h * 35 + c]) : (short)0;
        }
        V[t] = v;
    } else if (t < 16384 + 1024) {
        int f = t - 16384;
        int lane = f & 63, htile = f >> 6;
        int row = lane & 31;
        int h = htile * 32 + SWAP23(row);
        bf16x8 v;
#pragma unroll
        for (int i = 0; i < 8; ++i) v[i] = 0;
        if (lane < 32) {
#pragma unroll
            for (int l = 0; l < 7; ++l) v[l] = (short)f2bf(W1[l * 512 + h]);
            v[7] = (short)f2bf(b1[h]);
        }
        Wt[f] = v;
    }
}

// ---------------------------------------------------------------------------
// Kernel 2: main. 256 blocks x 256 threads (4 waves); block = 128 samples x
// 256 p, exactly 1 block/CU. Wave w: owns ptiles {2w,2w+1} x ALL 4 sample-
// tiles (acc[2][4] = 128 VGPR); in phase A it computes pre for sample-tile
// st=w, both 32-h subtiles of the chunk. Permuted Wt makes the pre-MFMA
// output directly the B-frag: store = 4x ds_write_b128, zero shuffles.
// One barrier per 64-h chunk; launch_bounds(256,1) -> no spill at ~270 VGPR.
// ---------------------------------------------------------------------------
__global__ __launch_bounds__(256, 1)
void torsion_main(const float* __restrict__ x,
                  const bf16x8* __restrict__ V, const bf16x8* __restrict__ Wt,
                  float* __restrict__ partials) {
    __shared__ __align__(16) u32 Gb[2][16][64 * 4];  // [buf][ks*4+st][lane dwords] = 32KB
    __shared__ float red[4][4][32];
    __shared__ float fin[2][2];

    const int tid  = threadIdx.x;
    const int lane = tid & 63;
    const int w    = tid >> 6;       // wave: ptile pair {2w,2w+1}; pre sample-tile st=w
    const int blk  = blockIdx.x;

    // x B-frag for sample-tile st=w: col = sample, lo half k=0..6 -> x, k=7 -> 1
    bf16x8 xf;
#pragma unroll
    for (int i = 0; i < 8; ++i) xf[i] = 0;
    if (lane < 32) {
        const float* xp = x + ((size_t)blk * 128 + w * 32 + lane) * 7;
#pragma unroll
        for (int l = 0; l < 7; ++l) xf[l] = (short)f2bf(xp[l]);
        xf[7] = (short)f2bf(1.0f);
    }

    f32x16 acc[2][4];
#pragma unroll
    for (int pt = 0; pt < 2; ++pt)
#pragma unroll
        for (int st = 0; st < 4; ++st)
#pragma unroll
            for (int e = 0; e < 16; ++e) acc[pt][st][e] = 0.0f;

    // g from a pre-MFMA result: 16 values -> 8 packed bf16 dwords.
    // Thanks to the SWAP23-permuted Wt rows, d[0..3] is the B-frag for the
    // even kstep and d[4..7] for the odd kstep of this 32-h subtile.
    auto compute_g = [&](const f32x16& p, u32 d[8]) {
#pragma unroll
        for (int j = 0; j < 8; ++j) {
            float t0 = __expf(-2.0f * fabsf(p[2 * j]));
            float r0 = fast_rcp(1.0f + t0);
            float g0 = 4.0f * t0 * r0 * r0;
            float t1 = __expf(-2.0f * fabsf(p[2 * j + 1]));
            float r1 = fast_rcp(1.0f + t1);
            float g1 = 4.0f * t1 * r1 * r1;
            d[j] = pack_bf16(g0, g1);
        }
    };

    // ---- prologue: chunk 0 pre + store; prefetch V(0), Wt(1) ----
    bf16x8 wt0 = Wt[0 * 64 + lane];          // chunk0 hs=0
    bf16x8 wt1 = Wt[1 * 64 + lane];          // chunk0 hs=1
    {
        f32x16 p0, p1;
#pragma unroll
        for (int e = 0; e < 16; ++e) { p0[e] = 0.0f; p1[e] = 0.0f; }
        p0 = __builtin_amdgcn_mfma_f32_32x32x16_bf16(wt0, xf, p0, 0, 0, 0);
        p1 = __builtin_amdgcn_mfma_f32_32x32x16_bf16(wt1, xf, p1, 0, 0, 0);
        u32 d0[8], d1[8];
        compute_g(p0, d0);
        compute_g(p1, d1);
        *reinterpret_cast<uint4*>(&Gb[0][0 * 4 + w][lane * 4]) = make_uint4(d0[0], d0[1], d0[2], d0[3]);
        *reinterpret_cast<uint4*>(&Gb[0][1 * 4 + w][lane * 4]) = make_uint4(d0[4], d0[5], d0[6], d0[7]);
        *reinterpret_cast<uint4*>(&Gb[0][2 * 4 + w][lane * 4]) = make_uint4(d1[0], d1[1], d1[2], d1[3]);
        *reinterpret_cast<uint4*>(&Gb[0][3 * 4 + w][lane * 4]) = make_uint4(d1[4], d1[5], d1[6], d1[7]);
    }
    bf16x8 vr[8];
#pragma unroll
    for (int ks = 0; ks < 4; ++ks) {
        const int fb = (ks * 8 + 2 * w) * 64 + lane;
        vr[ks * 2]     = V[fb];
        vr[ks * 2 + 1] = V[fb + 64];
    }
    wt0 = Wt[2 * 64 + lane];                 // chunk1 hs=0
    wt1 = Wt[3 * 64 + lane];                 // chunk1 hs=1
    __syncthreads();

    // ---- main loop: 8 chunks of 64 h ----
    for (int c = 0; c < 8; ++c) {
        const int buf = c & 1;

        // (1) pre-MFMAs for chunk c+1 (issued first -> complete first)
        f32x16 p0, p1;
        if (c < 7) {
#pragma unroll
            for (int e = 0; e < 16; ++e) { p0[e] = 0.0f; p1[e] = 0.0f; }
            p0 = __builtin_amdgcn_mfma_f32_32x32x16_bf16(wt0, xf, p0, 0, 0, 0);
            p1 = __builtin_amdgcn_mfma_f32_32x32x16_bf16(wt1, xf, p1, 0, 0, 0);
        }

        // (2) main MFMAs: 16 ds_read_b128 + 32 MFMA (matrix pipe ~1k cyc)
#pragma unroll
        for (int ks = 0; ks < 4; ++ks)
#pragma unroll
            for (int st = 0; st < 4; ++st) {
                bf16x8 g = *reinterpret_cast<const bf16x8*>(&Gb[buf][ks * 4 + st][lane * 4]);
                acc[0][st] = __builtin_amdgcn_mfma_f32_32x32x16_bf16(vr[ks * 2],     g, acc[0][st], 0, 0, 0);
                acc[1][st] = __builtin_amdgcn_mfma_f32_32x32x16_bf16(vr[ks * 2 + 1], g, acc[1][st], 0, 0, 0);
            }

        // (3) prefetch V(c+1), Wt(c+2) — consumed next iteration
        if (c < 7) {
#pragma unroll
            for (int ks = 0; ks < 4; ++ks) {
                const int fb = (((c + 1) * 4 + ks) * 8 + 2 * w) * 64 + lane;
                vr[ks * 2]     = V[fb];
                vr[ks * 2 + 1] = V[fb + 64];
            }
        }
        if (c < 6) {
            wt0 = Wt[((c + 2) * 2 + 0) * 64 + lane];
            wt1 = Wt[((c + 2) * 2 + 1) * 64 + lane];
        }

        // (4) g for chunk c+1: exp chain hides under the matrix pipe; store
        if (c < 7) {
            u32 d0[8], d1[8];
            compute_g(p0, d0);
            compute_g(p1, d1);
            *reinterpret_cast<uint4*>(&Gb[buf ^ 1][0 * 4 + w][lane * 4]) = make_uint4(d0[0], d0[1], d0[2], d0[3]);
            *reinterpret_cast<uint4*>(&Gb[buf ^ 1][1 * 4 + w][lane * 4]) = make_uint4(d0[4], d0[5], d0[6], d0[7]);
            *reinterpret_cast<uint4*>(&Gb[buf ^ 1][2 * 4 + w][lane * 4]) = make_uint4(d1[0], d1[1], d1[2], d1[3]);
            *reinterpret_cast<uint4*>(&Gb[buf ^ 1][3 * 4 + w][lane * 4]) = make_uint4(d1[4], d1[5], d1[6], d1[7]);
        }
        __syncthreads();
    }

    // ---- epilogue: D[p][sample]: col = sample; lane & lane^32 hold
    // complementary p-rows of the SAME sample. Partial over this wave's 2
    // ptiles; cross-wave sum via red LDS.
#pragma unroll
    for (int st = 0; st < 4; ++st) {
        float s = 0.0f;
#pragma unroll
        for (int pt = 0; pt < 2; ++pt)
#pragma unroll
            for (int e = 0; e < 16; ++e) s += acc[pt][st][e] * acc[pt][st][e];
        s += __shfl_xor(s, 32);
        if (lane < 32) red[w][st][lane] = s;
    }
    __syncthreads();

    if (tid < 128) {
        const int st = tid >> 5, col = tid & 31;
        float q = 6.0f * (red[0][st][col] + red[1][st][col] + red[2][st][col] + red[3][st][col]);
        float n = sqrtf(q + 1e-10f);
        float dd = n - KAPPA;
        float a = dd * dd, b = n;
#pragma unroll
        for (int m = 1; m <= 32; m <<= 1) {
            a += __shfl_xor(a, m);
            b += __shfl_xor(b, m);
        }
        if ((tid & 63) == 0) {
            fin[0][tid >> 6] = a;
            fin[1][tid >> 6] = b;
        }
    }
    __syncthreads();
    if (tid == 0) {
        partials[blk]        = fin[0][0] + fin[0][1];
        partials[NBLK + blk] = fin[1][0] + fin[1][1];
    }
}

// ---------------------------------------------------------------------------
// Kernel 3: finalize — deterministic sum of 256 per-block partials.
// ---------------------------------------------------------------------------
__global__ void finalize_k(const float* __restrict__ partials, float* __restrict__ out) {
    __shared__ float sl[256], sn[256];
    int tid = threadIdx.x;
    sl[tid] = partials[tid];
    sn[tid] = partials[NBLK + tid];
    __syncthreads();
    for (int st = 128; st > 0; st >>= 1) {
        if (tid < st) { sl[tid] += sl[tid + st]; sn[tid] += sn[tid + st]; }
        __syncthreads();
    }
    if (tid == 0) {
        out[0] = sl[0] / 32768.0f;
        out[1] = sn[0] / 32768.0f;
    }
}

// ---------------------------------------------------------------------------
extern "C" void kernel_launch(void* const* d_in, const int* in_sizes, int n_in,
                              void* d_out, int out_size, void* d_ws, size_t ws_size,
                              hipStream_t stream) {
    const float* x  = (const float*)d_in[0];
    const float* W1 = (const float*)d_in[1];
    const float* b1 = (const float*)d_in[2];
    const float* W2 = (const float*)d_in[3];
    // b2 (d_in[4]) unused: the Jacobian kills the bias.

    bf16x8* V        = (bf16x8*)d_ws;          // 16384 frags * 16 B = 256 KB
    bf16x8* Wt       = V + 16384;              // 1024 frags * 16 B = 16 KB
    float*  partials = (float*)(Wt + 1024);    // 512 floats

    build_v<<<68, 256, 0, stream>>>(W1, W2, b1, V, Wt);
    torsion_main<<<NBLK, 256, 0, stream>>>(x, V, Wt, partials);
    finalize_k<<<1, 256, 0, stream>>>(partials, (float*)d_out);
}